// Round 16
// baseline (234.198 us; speedup 1.0000x reference)
//
#include <hip/hip_runtime.h>

// ---------------- workspace layout (float offsets) ----------------
#define AFF_OFF   0u         // [2][1024 p][1024 q]
#define XC_OFF    2097152u   // [2][1024 p][1024 q]
#define K8_OFF    4194304u   // Ktab8 [81 cls][125 item][8] (pad cols 5..7 = 0)
#define BIAS_OFF  4275328u   // [32 l][3 cd][3 ch][3 cw]
#define PART_OFF  4276224u   // topq partials [2][32][3][1024]
#define ZP_OFF    4476928u   // zero page (1024 floats)
#define KC_OFF    4477952u   // w-boundary correction kernels [9 cls2][3 ch][2 ws][125]
#define PTAB_OFF  4484704u   // P = W2^T W1, [81 q2][81 q1]
// total 4491265 floats ~ 17.97 MB

#define SLOT 2160            // ring-slot stride (floats); 5 slots; slot(P) = (P+10)%5
#define KVQ_OFF 10800        // kv tables in LDS: [int f4 500][bnd f4 500][int t4 125][bnd t4 125]
#define KC_LDS  12050        // Kc tables in LDS: [bnd(2)][ws(2)][125] = 500

static __device__ __forceinline__ int imax(int a, int b){ return a > b ? a : b; }
static __device__ __forceinline__ int imin(int a, int b){ return a < b ? a : b; }

static __device__ __forceinline__ void ins3(float& a0, float& a1, float& a2, float v){
  if (v > a0){ a2 = a1; a1 = a0; a0 = v; }
  else if (v > a1){ a2 = a1; a1 = v; }
  else if (v > a2){ a2 = v; }
}

// 5-tap x 16-output row conv: window f[20] from 5 float4s, taps kq+k4
static __device__ __forceinline__ void fma80(const float4 a, const float4 b, const float4 c,
                                             const float4 d, const float4 e,
                                             const float4 kq, const float k4, float* acc){
  float f[20] = {a.x, a.y, a.z, a.w, b.x, b.y, b.z, b.w, c.x, c.y, c.z, c.w,
                 d.x, d.y, d.z, d.w, e.x, e.y, e.z, e.w};
  float kv5[5] = {kq.x, kq.y, kq.z, kq.w, k4};
  #pragma unroll
  for (int dw = 0; dw < 5; ++dw)
    #pragma unroll
    for (int j = 0; j < 16; ++j)
      acc[j] = fmaf(kv5[dw], f[j + dw], acc[j]);
}

#define GLL4(gsrc, ldst) __builtin_amdgcn_global_load_lds( \
    (const __attribute__((address_space(1))) void*)(gsrc), \
    (__attribute__((address_space(3))) void*)(ldst), 4, 0, 0)

// ============ K0: P = W2^T W1 (81x81) ============
__global__ __launch_bounds__(256) void ptab_k(const float* __restrict__ W1,
                                              const float* __restrict__ W2,
                                              float* __restrict__ ws){
  int tid = blockIdx.x * 256 + threadIdx.x;
  if (tid < 6561){
    int q2 = tid / 81, q1 = tid - (tid / 81) * 81;
    float s = 0.f;
    #pragma unroll
    for (int co = 0; co < 16; ++co)
      s = fmaf(W2[co * 81 + q2], W1[co * 81 + q1], s);
    ws[PTAB_OFF + tid] = s;
  }
}

// ============ K1: fused { gemm(+norms) | tab (P-based) } ============
__global__ __launch_bounds__(256) void prep_k(const float* __restrict__ xp,
                                              const float* __restrict__ xq,
                                              const float* __restrict__ W1,
                                              const float* __restrict__ B1,
                                              const float* __restrict__ W2,
                                              const float* __restrict__ B2,
                                              float* __restrict__ ws){
  __shared__ __align__(16) float shbuf[6564];    // gemm: As/Bs dbuf (4096); tab: P (6561)
  int bid0 = blockIdx.x;
  int t = threadIdx.x;

  if (bid0 >= 512){
    // ---------------- tab part (351 blocks), P staged in LDS ----------------
    float* P = shbuf;
    for (int i = t; i < 6561; i += 256) P[i] = ws[PTAB_OFF + i];
    __syncthreads();
    int tid = (bid0 - 512) * 256 + t;
    if (tid < 50625){
      int c = tid / 625, r = tid % 625;
      int cw = c % 3, ch = (c / 3) % 3, cd = (c / 9) % 3, cl = c / 27;
      int rw = r % 5, rh = (r / 5) % 5, rd = (r / 25) % 5, rl = r / 125;
      int al0 = imax(0, rl - 2), al1 = imin(2, rl);
      if (cl == 0) al0 = imax(al0, 1);
      if (cl == 2) al1 = imin(al1, 1);
      int ad0 = imax(0, rd - 2), ad1 = imin(2, rd);
      if (cd == 0) ad0 = imax(ad0, 1);
      if (cd == 2) ad1 = imin(ad1, 1);
      int ah0 = imax(0, rh - 2), ah1 = imin(2, rh);
      if (ch == 0) ah0 = imax(ah0, 1);
      if (ch == 2) ah1 = imin(ah1, 1);
      int aw0 = imax(0, rw - 2), aw1 = imin(2, rw);
      if (cw == 0) aw0 = imax(aw0, 1);
      if (cw == 2) aw1 = imin(aw1, 1);
      float s = 0.f;
      for (int a = al0; a <= al1; ++a)
        for (int bq = ad0; bq <= ad1; ++bq)
          for (int cq = ah0; cq <= ah1; ++cq)
            for (int dq = aw0; dq <= aw1; ++dq){
              int q2 = ((a * 3 + bq) * 3 + cq) * 3 + dq;
              int q1 = (((rl - a) * 3 + (rd - bq)) * 3 + (rh - cq)) * 3 + (rw - dq);
              s += P[q2 * 81 + q1];
            }
      int item = (r * 205) >> 10;           // r/5
      int j = r - item * 5;
      ws[K8_OFF + (size_t)c * 1000 + item * 8 + j] = s;
    } else if (tid < 51489){
      int t2 = tid - 50625;
      int l = t2 / 27, rest = t2 % 27;
      int cd = rest / 9, ch = (rest / 3) % 3, cw = rest % 3;
      float v = 0.f;
      for (int i = 0; i < 3; ++i){ int y = l + i - 1; if (y >= 0 && y < 32) v += B2[i]; }
      int jlo = (cd == 0) ? 1 : 0, jhi = (cd == 2) ? 1 : 2;
      int klo = (ch == 0) ? 1 : 0, khi = (ch == 2) ? 1 : 2;
      int mlo = (cw == 0) ? 1 : 0, mhi = (cw == 2) ? 1 : 2;
      for (int i = 0; i < 3; ++i){
        int y = l + i - 1; if (y < 0 || y >= 32) continue;
        for (int co = 0; co < 16; ++co){
          float b1e = 0.f;
          for (int i2 = 0; i2 < 3; ++i2){
            int y2 = y + i2 - 1; if (y2 >= 0 && y2 < 32) b1e += B1[i2 * 16 + co];
          }
          float S = 0.f;
          for (int j = jlo; j <= jhi; ++j)
            for (int k = klo; k <= khi; ++k)
              for (int m = mlo; m <= mhi; ++m)
                S += W2[co * 81 + ((i * 3 + j) * 3 + k) * 3 + m];
          v += b1e * S;
        }
      }
      ws[BIAS_OFF + t2] = v;
    } else if (tid < 52513){
      ws[ZP_OFF + (tid - 51489)] = 0.f;                 // zero page
    } else if (tid < 82888){
      int u = tid - 52513;                              // pad cols 5..7 of Ktab8
      int c = u / 375, r2 = u % 375;
      int item = r2 / 3, j = 5 + r2 % 3;
      ws[K8_OFF + (size_t)c * 1000 + item * 8 + j] = 0.f;
    } else if (tid < 89638){
      // ---- Kc correction tables: [cls2 9][ch 3][ws 2][125 traversal] ----
      int u = tid - 82888;
      int cls2 = u / 750, rest = u % 750;
      int ch = rest / 250, r2 = rest % 250;
      int wsd = r2 / 125, ut = r2 % 125;
      int rd, rl, rh;
      if (ut < 25){ rd = 0; rl = ut / 5; rh = ut % 5; }
      else { int g = ut - 25; rd = 1 + g / 25; int rr = g % 25; rl = rr / 5; rh = rr % 5; }
      int cl = cls2 / 3, cd = cls2 % 3;
      int al0 = imax(0, rl - 2), al1 = imin(2, rl);
      if (cl == 0) al0 = imax(al0, 1);
      if (cl == 2) al1 = imin(al1, 1);
      int ad0 = imax(0, rd - 2), ad1 = imin(2, rd);
      if (cd == 0) ad0 = imax(ad0, 1);
      if (cd == 2) ad1 = imin(ad1, 1);
      int ah0 = imax(0, rh - 2), ah1 = imin(2, rh);
      if (ch == 0) ah0 = imax(ah0, 1);
      if (ch == 2) ah1 = imin(ah1, 1);
      int dq = wsd ? 2 : 0;           // excluded conv2 w-tap
      int q1w = wsd ? 0 : 2;          // surviving W1 w-tap (zero-pad kills others)
      float s = 0.f;
      for (int a = al0; a <= al1; ++a)
        for (int bq = ad0; bq <= ad1; ++bq)
          for (int cq = ah0; cq <= ah1; ++cq){
            int q2 = ((a * 3 + bq) * 3 + cq) * 3 + dq;
            int q1 = (((rl - a) * 3 + (rd - bq)) * 3 + (rh - cq)) * 3 + q1w;
            s += P[q2 * 81 + q1];
          }
      ws[KC_OFF + u] = s;
    }
    return;
  }

  // ---------------- gemm part (512 blocks), norms fused ----------------
  int bid = (bid0 & 7) * 64 + (bid0 >> 3);    // XCD swizzle (512 % 8 == 0)
  int qi = bid & 15, pi = (bid >> 4) & 15, b = bid >> 8;
  const float* A = xp + (size_t)b * 262144;   // [c][p]
  const float* B = xq + (size_t)b * 262144;   // [c][q]
  float* C = ws + AFF_OFF + (size_t)b * 1048576;
  int tx = t & 15, ty = t >> 4;
  int row = t >> 4, col = (t & 15) * 4;
  float* As0 = shbuf;            // [16][64]
  float* As1 = shbuf + 1024;
  float* Bs0 = shbuf + 2048;
  float* Bs1 = shbuf + 3072;
  const float* Ag = A + (size_t)row * 1024 + pi * 64 + col;
  const float* Bg = B + (size_t)row * 1024 + qi * 64 + col;
  float4 ra = *(const float4*)Ag;
  float4 rb = *(const float4*)Bg;
  *(float4*)&As0[row * 64 + col] = ra;
  *(float4*)&Bs0[row * 64 + col] = rb;
  __syncthreads();
  float acc[4][4] = {};
  float na[4] = {}, nb[4] = {};
  const float* Asc = As0; const float* Bsc = Bs0;
  float* Asn = As1; float* Bsn = Bs1;
  for (int k0 = 16; k0 <= 256; k0 += 16){
    if (k0 < 256){
      ra = *(const float4*)(Ag + (size_t)k0 * 1024);
      rb = *(const float4*)(Bg + (size_t)k0 * 1024);
    }
    #pragma unroll
    for (int kk = 0; kk < 16; ++kk){
      float4 av = *(const float4*)&Asc[kk * 64 + ty * 4];
      float4 bv = *(const float4*)&Bsc[kk * 64 + tx * 4];
      float a4[4] = {av.x, av.y, av.z, av.w};
      float b4[4] = {bv.x, bv.y, bv.z, bv.w};
      #pragma unroll
      for (int i = 0; i < 4; ++i){
        na[i] = fmaf(a4[i], a4[i], na[i]);
        nb[i] = fmaf(b4[i], b4[i], nb[i]);
        #pragma unroll
        for (int j = 0; j < 4; ++j)
          acc[i][j] = fmaf(a4[i], b4[j], acc[i][j]);
      }
    }
    if (k0 < 256){
      *(float4*)&Asn[row * 64 + col] = ra;
      *(float4*)&Bsn[row * 64 + col] = rb;
      __syncthreads();
      float* tmp;
      tmp = (float*)Asc; Asc = Asn; Asn = tmp;
      tmp = (float*)Bsc; Bsc = Bsn; Bsn = tmp;
    }
  }
  float iva[4], ivb[4];
  #pragma unroll
  for (int i = 0; i < 4; ++i){
    iva[i] = 1.0f / fmaxf(sqrtf(na[i]), 1e-12f);
    ivb[i] = 1.0f / fmaxf(sqrtf(nb[i]), 1e-12f);
  }
  #pragma unroll
  for (int i = 0; i < 4; ++i){
    float iva_i = iva[i];
    float4 v = make_float4(acc[i][0] * iva_i * ivb[0], acc[i][1] * iva_i * ivb[1],
                           acc[i][2] * iva_i * ivb[2], acc[i][3] * iva_i * ivb[3]);
    *(float4*)&C[(size_t)(pi * 64 + ty * 4 + i) * 1024 + qi * 64 + tx * 4] = v;
  }
}

// ============ K2: composed 5^4 conv; 16-wide lanes (80 FMA / 7 LDS per row) ============
// lane: t = wv(2) | grp(4) | hsel(1) | whalf(1); unit = (hl = wv*2+hsel, w0 = whalf*16)
// 16 grp-lanes split the 125 (dl,dd,dh) rows; reduce-scatter over grp bits (shfl 4/8/16/32).
__global__ __launch_bounds__(256, 3) void conv_k(float* __restrict__ ws){
  __shared__ __align__(16) float slots[5 * SLOT + 1750];   // 12550 f = 50.2 KB -> 3 blocks/CU

  int bid0 = blockIdx.x;
  int t = threadIdx.x;
  int bid, nsteps, dstart;
  if (bid0 < 256){                      // double block: units 2p, 2p+1 (shared b,l0,hq)
    int c = bid0 & 7, r = bid0 >> 3;
    int p = c * 64 + r;                 // pair id, XCD-chunked
    bid = 2 * p;
    nsteps = 16;
    dstart = ((bid >> 1) & 1) * 16;
  } else {                              // single block
    int s = bid0 - 256;
    int c = s & 7, q = s >> 3;
    int p = c * 64 + 32 + (q >> 1);
    bid = 2 * p + (q & 1);
    nsteps = 8;
    dstart = (bid & 3) * 8;
  }
  int hq = (bid >> 2) & 3, l0 = (bid >> 4) & 31, b = bid >> 9;
  int h0 = hq * 8;
  const float* affB = ws + AFF_OFF + (size_t)b * 1048576;
  float* xc = ws + XC_OFF + (size_t)b * 1048576;
  const float* K8G = ws + K8_OFF;
  const float* KCg = ws + KC_OFF;
  const float* bias = ws + BIAS_OFF;
  const float* zp = ws + ZP_OFF;

  int cl = (l0 == 0) ? 0 : (l0 == 31) ? 2 : 1;
  int chB = (hq == 0) ? 0 : (hq == 3) ? 2 : 1;    // boundary-row h class (1 if none)

  // A-phase lane constants
  int wv = t >> 6;
  int whalf = t & 1, hsel = (t >> 1) & 1, g = (t >> 2) & 15;
  int hl = wv * 2 + hsel;
  int hA = h0 + hl;
  int chA = (hA == 0) ? 0 : (hA == 31) ? 2 : 1;
  int w0c = whalf * 16;
  bool isBnd = (hq == 0 && hl == 0) || (hq == 3 && hl == 7);
  int bndoff4 = isBnd ? 500 : 0;
  int bndoff1 = isBnd ? 125 : 0;
  int wlocal = ((g & 1) << 3) | ((g & 2) << 1) | ((g & 4) >> 1) | ((g & 8) >> 3);
  int wA = w0c + wlocal;

  // boundary-column (corr) lane constants
  int outB = t >> 4, subB = t & 15;
  int hlB = outB >> 1, wx31 = outB & 1;
  int hB = h0 + hlB;
  int chB2 = (hB == 0) ? 0 : (hB == 31) ? 2 : 1;
  int cwB = wx31 ? 2 : 0;
  int colB = wx31 ? 33 : 2;                        // aff column w'=31 / w'=0 in 36-wide rows
  bool isBndB = (hq == 0 && hlB == 0) || (hq == 3 && hlB == 7);
  int kcBase = KC_LDS + (isBndB ? 250 : 0) + wx31 * 125;
  // base handoff: lane (in wave) holding interior value at (hB, w=0/31):
  //   w=0: grp=0,whalf=0 -> lane 2*hsel;  w=31: grp=15,whalf=1 -> lane 61+2*hsel
  int local = t & 63;
  int hs_ = (local >> 5) & 1;
  int wx_ = (local >> 4) & 1;
  int srcL = wx_ ? (61 + 2 * hs_) : (2 * hs_);

  // staging global offsets (9 rounds x 256 lanes = 2160 floats/plane)
  int o0, o1, o2, o3, o4, o5, o6, o7, o8;
#define PRE(r) { int flat = (r)*256 + t; \
    int wi = flat % 36; int rest = flat / 36; int hi = rest % 12; int dl2 = rest / 12; \
    int lp_ = l0 + dl2 - 2, hp_ = h0 + hi - 2, wp_ = wi - 2; \
    bool ok = ((unsigned)lp_ < 32u) && ((unsigned)hp_ < 32u) && ((unsigned)wp_ < 32u); \
    o##r = ok ? (lp_ * 32768 + hp_ * 32 + wp_) : -1; }
  PRE(0) PRE(1) PRE(2) PRE(3) PRE(4) PRE(5) PRE(6) PRE(7) PRE(8)
#undef PRE

#define STG(r, sp_) { const float* s_ = (pOK_ && o##r >= 0) ? (affB + o##r + dpo_) : zp; \
    GLL4(s_, sp_ + (r)*256 + t); }
#define STAGE(si_, dpv_) do { \
    int dp_ = (dpv_); bool pOK_ = ((unsigned)dp_ < 32u); int dpo_ = dp_ * 1024; \
    float* sp_ = slots + (si_) * SLOT; \
    STG(0, sp_) STG(1, sp_) STG(2, sp_) STG(3, sp_) \
    STG(4, sp_) STG(5, sp_) STG(6, sp_) STG(7, sp_) \
    if (t < 112) sp_[2048 + t] = (pOK_ && o8 >= 0) ? affB[o8 + dpo_] : 0.f; \
  } while (0)

  // kv tables (traversal order) + Kc tables; SEPARATE prefix-aligned loops
  // (global_load_lds writes firstlane-base + laneid*4 — active lanes MUST be a
  //  per-wave prefix with linear offsets; never branch mid-wave to a new base.)
#define LOADKV(cdv_) do { int cd_ = (cdv_); \
    int clsI_ = ((cl * 3 + cd_) * 3 + 1) * 3 + 1; \
    int clsB_ = ((cl * 3 + cd_) * 3 + chB) * 3 + 1; \
    for (int r_ = 0; r_ < 5; ++r_){ \
      int i_ = r_ * 256 + t; \
      if (i_ < 1250){ \
        int u_, j_, cls_; \
        if (i_ < 500){ u_ = i_ >> 2; j_ = i_ & 3; cls_ = clsI_; } \
        else if (i_ < 1000){ u_ = (i_ - 500) >> 2; j_ = i_ & 3; cls_ = clsB_; } \
        else if (i_ < 1125){ u_ = i_ - 1000; j_ = 4; cls_ = clsI_; } \
        else { u_ = i_ - 1125; j_ = 4; cls_ = clsB_; } \
        int dl_, dd_, dh_; \
        if (u_ < 25){ dd_ = 0; dl_ = u_ / 5; dh_ = u_ - dl_ * 5; } \
        else { int g_ = u_ - 25; dd_ = 1 + g_ / 25; int r2_ = g_ - (dd_ - 1) * 25; \
               dl_ = r2_ / 5; dh_ = r2_ - dl_ * 5; } \
        int m_ = dl_ * 25 + dd_ * 5 + dh_; \
        GLL4(K8G + (size_t)cls_ * 1000 + m_ * 8 + j_, slots + KVQ_OFF + i_); \
      } \
    } \
    for (int r_ = 0; r_ < 2; ++r_){ \
      int i2_ = r_ * 256 + t; \
      if (i2_ < 500){ \
        int bnd_ = (i2_ >= 250) ? 1 : 0; \
        int u2_ = i2_ - bnd_ * 250; \
        int chS_ = bnd_ ? chB : 1; \
        GLL4(KCg + (size_t)(cl * 3 + cd_) * 750 + chS_ * 250 + u2_, \
             slots + KC_LDS + i2_); \
      } \
    } \
  } while (0)

#define MROW { \
    const float* rp = slots + addr; \
    float4 q0 = *(const float4*)rp; \
    float4 q1 = *(const float4*)(rp + 4); \
    float4 q2 = *(const float4*)(rp + 8); \
    float4 q3 = *(const float4*)(rp + 12); \
    float4 q4v = *(const float4*)(rp + 16); \
    float4 kqv = *(const float4*)(slots + kvqA); \
    float k4v = slots[kv4A]; \
    fma80(q0, q1, q2, q3, q4v, kqv, k4v, acc); }

  int cdCur = (dstart == 0) ? 0 : 1;
  LOADKV(cdCur);
  STAGE((dstart + 8)  % 5, dstart - 2);
  STAGE((dstart + 9)  % 5, dstart - 1);
  STAGE((dstart + 10) % 5, dstart);
  STAGE((dstart + 11) % 5, dstart + 1);
  STAGE((dstart + 12) % 5, dstart + 2);
  asm volatile("s_waitcnt vmcnt(0)" ::: "memory");
  __syncthreads();

  for (int s8 = 0; s8 < nsteps; ++s8){
    int d = dstart + s8;
    int cd = (d == 0) ? 0 : (d == 31) ? 2 : 1;
    if (cd != cdCur){                               // block-uniform, rare
      cdCur = cd;
      LOADKV(cd);
      asm volatile("s_waitcnt vmcnt(0)" ::: "memory");
      __syncthreads();
    }
    int scomp = (d + 3) % 5;                        // slot of plane d-2 (dd=0)

    float acc[16] = {0.f, 0.f, 0.f, 0.f, 0.f, 0.f, 0.f, 0.f,
                     0.f, 0.f, 0.f, 0.f, 0.f, 0.f, 0.f, 0.f};
    float corr = 0.f;

    // ---- phase 1: rows u=g, u=g+16 (all dd=0 reads done here) + corr rd=0 taps ----
    {
      int dlp = (g * 205) >> 10;
      int dhp = g - dlp * 5;
      int sip = scomp;
      int addr = sip * SLOT + (dlp * 12 + hl + dhp) * 36 + w0c;
      int kvqA = KVQ_OFF + bndoff4 + g * 4;
      int kv4A = KVQ_OFF + 1000 + bndoff1 + g;
      MROW
      addr += 1332; dhp += 1; dlp += 3; kvqA += 64; kv4A += 16;
      if (dhp >= 5){ dhp -= 5; dlp += 1; addr += 252; }
      if (dlp >= 5){ dlp -= 5; sip += 1; if (sip >= 5){ sip -= 5; addr -= 5 * SLOT; } }
      MROW
      int u = subB;
      #pragma unroll
      for (int k = 0; k < 2; ++k){
        if (u < 25){
          int rl = (u * 205) >> 10, rh = u - rl * 5;
          float kcv = slots[kcBase + u];
          float av = slots[scomp * SLOT + (rl * 12 + hlB + rh) * 36 + colB];
          corr = fmaf(kcv, av, corr);
        }
        u += 16;
      }
    }
    __syncthreads();                     // all reads of slot scomp done
    if (s8 < nsteps - 1) STAGE(scomp, d + 3);   // async: plane d+3 into slot scomp

    // ---- phase 2: rows u = g+32 .. 124 step 16 + corr rd>=1 taps ----
    {
      int u = g + 32;                    // dd == 1 for all lanes at start
      int rem = u - 25;
      int dlp = (rem * 205) >> 10;
      int dhp = rem - dlp * 5;
      int sip = scomp + 1; if (sip >= 5) sip -= 5;
      int addr = sip * SLOT + (dlp * 12 + hl + dhp) * 36 + w0c;
      int kvqA = KVQ_OFF + bndoff4 + u * 4;
      int kv4A = KVQ_OFF + 1000 + bndoff1 + u;
      for (; u < 125; u += 16){
        MROW
        addr += 1332; dhp += 1; dlp += 3; kvqA += 64; kv4A += 16;
        if (dhp >= 5){ dhp -= 5; dlp += 1; addr += 252; }
        if (dlp >= 5){ dlp -= 5; sip += 1; if (sip >= 5){ sip -= 5; addr -= 5 * SLOT; } }
      }
      int u2 = subB;
      #pragma unroll
      for (int k = 0; k < 7; ++k){
        if (u2 < 100){
          int rd = 1 + ((u2 * 41) >> 10);
          int rr = u2 - (rd - 1) * 25;
          int rl = (rr * 205) >> 10, rh = rr - rl * 5;
          int si2 = scomp + rd; if (si2 >= 5) si2 -= 5;
          float kcv = slots[kcBase + 25 + u2];
          float av = slots[si2 * SLOT + (rl * 12 + hlB + rh) * 36 + colB];
          corr = fmaf(kcv, av, corr);
        }
        u2 += 16;
      }
    }

    // ---- corr reduction (16 sub-lanes) ----
    corr += __shfl_xor(corr, 1);
    corr += __shfl_xor(corr, 2);
    corr += __shfl_xor(corr, 4);
    corr += __shfl_xor(corr, 8);

    // ---- A reduce-scatter butterfly over grp bits (15 shfl) ----
    float r;
    {
      bool c1 = (g & 1) != 0;
      float s8v[8], k8v[8];
      #pragma unroll
      for (int j = 0; j < 8; ++j){
        s8v[j] = c1 ? acc[j] : acc[j + 8];
        k8v[j] = c1 ? acc[j + 8] : acc[j];
      }
      #pragma unroll
      for (int j = 0; j < 8; ++j) k8v[j] += __shfl_xor(s8v[j], 4);
      bool c2 = (g & 2) != 0;
      float s4v[4], q4s[4];
      #pragma unroll
      for (int j = 0; j < 4; ++j){
        s4v[j] = c2 ? k8v[j] : k8v[j + 4];
        q4s[j] = c2 ? k8v[j + 4] : k8v[j];
      }
      #pragma unroll
      for (int j = 0; j < 4; ++j) q4s[j] += __shfl_xor(s4v[j], 8);
      bool c3 = (g & 4) != 0;
      float s2v[2], k2v[2];
      #pragma unroll
      for (int j = 0; j < 2; ++j){
        s2v[j] = c3 ? q4s[j] : q4s[j + 2];
        k2v[j] = c3 ? q4s[j + 2] : q4s[j];
      }
      #pragma unroll
      for (int j = 0; j < 2; ++j) k2v[j] += __shfl_xor(s2v[j], 16);
      bool c4 = (g & 8) != 0;
      float s1v = c4 ? k2v[0] : k2v[1];
      float k1v = c4 ? k2v[1] : k2v[0];
      r = k1v + __shfl_xor(s1v, 32);
    }

    // ---- base handoff: boundary-column groups pull interior value via shfl ----
    float baseR = __shfl(r, srcL);

    // ---- stores ----
    if (wA != 0 && wA != 31){
      float bvA = bias[l0 * 27 + cd * 9 + chA * 3 + 1];
      xc[(size_t)(l0 * 32 + d) * 1024 + hA * 32 + wA] = r + bvA;
    }
    if (subB == 0){
      float bvB = bias[l0 * 27 + cd * 9 + chB2 * 3 + cwB];
      xc[(size_t)(l0 * 32 + d) * 1024 + hB * 32 + (wx31 ? 31 : 0)] = baseR - corr + bvB;
    }

    asm volatile("s_waitcnt vmcnt(0)" ::: "memory");   // staged plane landed
    __syncthreads();
  }
#undef STG
#undef STAGE
#undef LOADKV
#undef MROW
}

// ============ K3: fused { valp top3 | valq stage1 } (no atomics) ============
__global__ __launch_bounds__(256) void top1_k(const float* __restrict__ ws, float* __restrict__ out){
  const float* xc = ws + XC_OFF;
  int bid = blockIdx.x;
  int t = threadIdx.x;

  if (bid < 512){
    // ---- valp: top3 over q per (b,p); wave per row ----
    int wid = bid * 4 + (t >> 6);
    int lane = t & 63;
    int b = wid >> 10, p = wid & 1023;
    const float4* row4 = (const float4*)(xc + (size_t)b * 1048576 + (size_t)p * 1024);
    float a0 = -3.4e38f, a1 = a0, a2 = a0;
    #pragma unroll
    for (int j = 0; j < 4; ++j){
      float4 v = row4[j * 64 + lane];
      ins3(a0, a1, a2, v.x); ins3(a0, a1, a2, v.y);
      ins3(a0, a1, a2, v.z); ins3(a0, a1, a2, v.w);
    }
    for (int off = 32; off; off >>= 1){
      float b0 = __shfl_xor(a0, off), b1 = __shfl_xor(a1, off), b2 = __shfl_xor(a2, off);
      ins3(a0, a1, a2, b0); ins3(a0, a1, a2, b1); ins3(a0, a1, a2, b2);
    }
    if (lane < 3){
      float v = (lane == 0) ? a0 : (lane == 1) ? a1 : a2;
      out[b * 3072 + lane * 1024 + p] = v;
    }
    return;
  }

  // ---- valq stage 1: partial top3 over 32 p's per (b,q) ----
  float* part = (float*)ws + PART_OFF;
  int b2 = bid - 512;                        // 256: b(2) x pc(32) x qq(4)
  int qq = b2 & 3, pc = (b2 >> 2) & 31, b = b2 >> 7;
  int q = qq * 256 + t;
  const float* base = xc + (size_t)b * 1048576 + q;
  float a0 = -3.4e38f, a1 = a0, a2 = a0;
  #pragma unroll 4
  for (int i = 0; i < 32; ++i) ins3(a0, a1, a2, base[(size_t)(pc * 32 + i) * 1024]);
  part[(size_t)((b * 32 + pc) * 3 + 0) * 1024 + q] = a0;
  part[(size_t)((b * 32 + pc) * 3 + 1) * 1024 + q] = a1;
  part[(size_t)((b * 32 + pc) * 3 + 2) * 1024 + q] = a2;
}

// ============ K4: valq stage 2 — 8 lanes per output, shfl-merged ============
__global__ __launch_bounds__(256) void top2_k(const float* __restrict__ ws, float* __restrict__ out){
  const float* part = ws + PART_OFF;
  int gid = blockIdx.x * 256 + threadIdx.x;   // 16384 = 2048 outputs x 8 lanes
  int sub = gid & 7;
  int oidx = gid >> 3;
  int b = oidx >> 10, q = oidx & 1023;
  float a0 = -3.4e38f, a1 = a0, a2 = a0;
  #pragma unroll
  for (int i = 0; i < 12; ++i){
    int c = sub + i * 8;
    ins3(a0, a1, a2, part[(size_t)(b * 96 + c) * 1024 + q]);
  }
  #pragma unroll
  for (int off = 1; off <= 4; off <<= 1){
    float b0 = __shfl_xor(a0, off), b1 = __shfl_xor(a1, off), b2 = __shfl_xor(a2, off);
    ins3(a0, a1, a2, b0); ins3(a0, a1, a2, b1); ins3(a0, a1, a2, b2);
  }
  if (sub == 0){
    out[6144 + b * 3072 + q] = a0;
    out[6144 + b * 3072 + 1024 + q] = a1;
    out[6144 + b * 3072 + 2048 + q] = a2;
  }
}

extern "C" void kernel_launch(void* const* d_in, const int* in_sizes, int n_in,
                              void* d_out, int out_size, void* d_ws, size_t ws_size,
                              hipStream_t stream){
  const float* xp = (const float*)d_in[0];
  const float* xq = (const float*)d_in[1];
  const float* W1 = (const float*)d_in[2];
  const float* B1 = (const float*)d_in[3];
  const float* W2 = (const float*)d_in[4];
  const float* B2 = (const float*)d_in[5];
  float* out = (float*)d_out;
  float* ws = (float*)d_ws;
  hipLaunchKernelGGL(ptab_k, dim3(26),  dim3(256), 0, stream, W1, W2, ws);
  hipLaunchKernelGGL(prep_k, dim3(863), dim3(256), 0, stream, xp, xq, W1, B1, W2, B2, ws);
  hipLaunchKernelGGL(conv_k, dim3(768), dim3(256), 0, stream, ws);
  hipLaunchKernelGGL(top1_k, dim3(768), dim3(256), 0, stream, ws, out);
  hipLaunchKernelGGL(top2_k, dim3(64),  dim3(256), 0, stream, ws, out);
}

// Round 17
// 199.262 us; speedup vs baseline: 1.1753x; 1.1753x over previous
//
#include <hip/hip_runtime.h>

// ---------------- workspace layout (float offsets) ----------------
#define AFF_OFF   0u         // [2][1024 p][1024 q]
#define XC_OFF    2097152u   // [2][1024 p][1024 q]
#define K8_OFF    4194304u   // Ktab8 [81 cls][125 item][8] (pad cols 5..7 = 0)
#define BIAS_OFF  4275328u   // [32 l][3 cd][3 ch][3 cw]
#define PART_OFF  4276224u   // topq partials [2][32][3][1024]
#define ZP_OFF    4476928u   // zero page (1024 floats)
#define KC_OFF    4477952u   // w-boundary correction kernels [9 cls2][3 ch][2 ws][125]
#define PTAB_OFF  4484704u   // P = W2^T W1, [81 q2][81 q1]
// total 4491265 floats ~ 17.97 MB

#define SLOT 2160            // ring-slot stride (floats); 5 slots; slot(P) = (P+10)%5
#define KVQ_OFF 10800        // kv tables in LDS: [int f4 500][bnd f4 500][int t4 125][bnd t4 125]
#define KC_LDS  12050        // Kc tables in LDS: [bnd(2)][ws(2)][125] = 500

static __device__ __forceinline__ int imax(int a, int b){ return a > b ? a : b; }
static __device__ __forceinline__ int imin(int a, int b){ return a < b ? a : b; }

static __device__ __forceinline__ void ins3(float& a0, float& a1, float& a2, float v){
  if (v > a0){ a2 = a1; a1 = a0; a0 = v; }
  else if (v > a1){ a2 = a1; a1 = v; }
  else if (v > a2){ a2 = v; }
}

// 5-tap x 16-output row conv: window f[20] from 5 float4s, taps kq+k4
static __device__ __forceinline__ void fma80(const float4 a, const float4 b, const float4 c,
                                             const float4 d, const float4 e,
                                             const float4 kq, const float k4, float* acc){
  float f[20] = {a.x, a.y, a.z, a.w, b.x, b.y, b.z, b.w, c.x, c.y, c.z, c.w,
                 d.x, d.y, d.z, d.w, e.x, e.y, e.z, e.w};
  float kv5[5] = {kq.x, kq.y, kq.z, kq.w, k4};
  #pragma unroll
  for (int dw = 0; dw < 5; ++dw)
    #pragma unroll
    for (int j = 0; j < 16; ++j)
      acc[j] = fmaf(kv5[dw], f[j + dw], acc[j]);
}

#define GLL4(gsrc, ldst) __builtin_amdgcn_global_load_lds( \
    (const __attribute__((address_space(1))) void*)(gsrc), \
    (__attribute__((address_space(3))) void*)(ldst), 4, 0, 0)

// ============ K0: P = W2^T W1 (81x81) ============
__global__ __launch_bounds__(256) void ptab_k(const float* __restrict__ W1,
                                              const float* __restrict__ W2,
                                              float* __restrict__ ws){
  int tid = blockIdx.x * 256 + threadIdx.x;
  if (tid < 6561){
    int q2 = tid / 81, q1 = tid - (tid / 81) * 81;
    float s = 0.f;
    #pragma unroll
    for (int co = 0; co < 16; ++co)
      s = fmaf(W2[co * 81 + q2], W1[co * 81 + q1], s);
    ws[PTAB_OFF + tid] = s;
  }
}

// ============ K1: fused { gemm(+norms) | tab (P-based, W2 staged) } ============
__global__ __launch_bounds__(256) void prep_k(const float* __restrict__ xp,
                                              const float* __restrict__ xq,
                                              const float* __restrict__ W1,
                                              const float* __restrict__ B1,
                                              const float* __restrict__ W2,
                                              const float* __restrict__ B2,
                                              float* __restrict__ ws){
  __shared__ __align__(16) float shbuf[7860];    // gemm: As/Bs dbuf (4096); tab: P (6561) + W2 (1296)
  int bid0 = blockIdx.x;
  int t = threadIdx.x;

  if (bid0 >= 512){
    // ---------------- tab part (351 blocks), P + W2 staged in LDS ----------------
    float* P = shbuf;
    float* sW2b = shbuf + 6561;
    for (int i = t; i < 6561; i += 256) P[i] = ws[PTAB_OFF + i];
    for (int i = t; i < 1296; i += 256) sW2b[i] = W2[i];
    __syncthreads();
    int tid = (bid0 - 512) * 256 + t;
    if (tid < 50625){
      int c = tid / 625, r = tid % 625;
      int cw = c % 3, ch = (c / 3) % 3, cd = (c / 9) % 3, cl = c / 27;
      int rw = r % 5, rh = (r / 5) % 5, rd = (r / 25) % 5, rl = r / 125;
      int al0 = imax(0, rl - 2), al1 = imin(2, rl);
      if (cl == 0) al0 = imax(al0, 1);
      if (cl == 2) al1 = imin(al1, 1);
      int ad0 = imax(0, rd - 2), ad1 = imin(2, rd);
      if (cd == 0) ad0 = imax(ad0, 1);
      if (cd == 2) ad1 = imin(ad1, 1);
      int ah0 = imax(0, rh - 2), ah1 = imin(2, rh);
      if (ch == 0) ah0 = imax(ah0, 1);
      if (ch == 2) ah1 = imin(ah1, 1);
      int aw0 = imax(0, rw - 2), aw1 = imin(2, rw);
      if (cw == 0) aw0 = imax(aw0, 1);
      if (cw == 2) aw1 = imin(aw1, 1);
      float s = 0.f;
      for (int a = al0; a <= al1; ++a)
        for (int bq = ad0; bq <= ad1; ++bq)
          for (int cq = ah0; cq <= ah1; ++cq)
            for (int dq = aw0; dq <= aw1; ++dq){
              int q2 = ((a * 3 + bq) * 3 + cq) * 3 + dq;
              int q1 = (((rl - a) * 3 + (rd - bq)) * 3 + (rh - cq)) * 3 + (rw - dq);
              s += P[q2 * 81 + q1];
            }
      int item = (r * 205) >> 10;           // r/5
      int j = r - item * 5;
      ws[K8_OFF + (size_t)c * 1000 + item * 8 + j] = s;
    } else if (tid < 51489){
      int t2 = tid - 50625;
      int l = t2 / 27, rest = t2 % 27;
      int cd = rest / 9, ch = (rest / 3) % 3, cw = rest % 3;
      float v = 0.f;
      for (int i = 0; i < 3; ++i){ int y = l + i - 1; if (y >= 0 && y < 32) v += B2[i]; }
      int jlo = (cd == 0) ? 1 : 0, jhi = (cd == 2) ? 1 : 2;
      int klo = (ch == 0) ? 1 : 0, khi = (ch == 2) ? 1 : 2;
      int mlo = (cw == 0) ? 1 : 0, mhi = (cw == 2) ? 1 : 2;
      for (int i = 0; i < 3; ++i){
        int y = l + i - 1; if (y < 0 || y >= 32) continue;
        for (int co = 0; co < 16; ++co){
          float b1e = 0.f;
          for (int i2 = 0; i2 < 3; ++i2){
            int y2 = y + i2 - 1; if (y2 >= 0 && y2 < 32) b1e += B1[i2 * 16 + co];
          }
          float S = 0.f;
          for (int j = jlo; j <= jhi; ++j)
            for (int k = klo; k <= khi; ++k)
              for (int m = mlo; m <= mhi; ++m)
                S += sW2b[co * 81 + ((i * 3 + j) * 3 + k) * 3 + m];
          v += b1e * S;
        }
      }
      ws[BIAS_OFF + t2] = v;
    } else if (tid < 52513){
      ws[ZP_OFF + (tid - 51489)] = 0.f;                 // zero page
    } else if (tid < 82888){
      int u = tid - 52513;                              // pad cols 5..7 of Ktab8
      int c = u / 375, r2 = u % 375;
      int item = r2 / 3, j = 5 + r2 % 3;
      ws[K8_OFF + (size_t)c * 1000 + item * 8 + j] = 0.f;
    } else if (tid < 89638){
      // ---- Kc correction tables: [cls2 9][ch 3][ws 2][125 traversal] ----
      int u = tid - 82888;
      int cls2 = u / 750, rest = u % 750;
      int ch = rest / 250, r2 = rest % 250;
      int wsd = r2 / 125, ut = r2 % 125;
      int rd, rl, rh;
      if (ut < 25){ rd = 0; rl = ut / 5; rh = ut % 5; }
      else { int g = ut - 25; rd = 1 + g / 25; int rr = g % 25; rl = rr / 5; rh = rr % 5; }
      int cl = cls2 / 3, cd = cls2 % 3;
      int al0 = imax(0, rl - 2), al1 = imin(2, rl);
      if (cl == 0) al0 = imax(al0, 1);
      if (cl == 2) al1 = imin(al1, 1);
      int ad0 = imax(0, rd - 2), ad1 = imin(2, rd);
      if (cd == 0) ad0 = imax(ad0, 1);
      if (cd == 2) ad1 = imin(ad1, 1);
      int ah0 = imax(0, rh - 2), ah1 = imin(2, rh);
      if (ch == 0) ah0 = imax(ah0, 1);
      if (ch == 2) ah1 = imin(ah1, 1);
      int dq = wsd ? 2 : 0;           // excluded conv2 w-tap
      int q1w = wsd ? 0 : 2;          // surviving W1 w-tap (zero-pad kills others)
      float s = 0.f;
      for (int a = al0; a <= al1; ++a)
        for (int bq = ad0; bq <= ad1; ++bq)
          for (int cq = ah0; cq <= ah1; ++cq){
            int q2 = ((a * 3 + bq) * 3 + cq) * 3 + dq;
            int q1 = (((rl - a) * 3 + (rd - bq)) * 3 + (rh - cq)) * 3 + q1w;
            s += P[q2 * 81 + q1];
          }
      ws[KC_OFF + u] = s;
    }
    return;
  }

  // ---------------- gemm part (512 blocks), norms fused ----------------
  int bid = (bid0 & 7) * 64 + (bid0 >> 3);    // XCD swizzle (512 % 8 == 0)
  int qi = bid & 15, pi = (bid >> 4) & 15, b = bid >> 8;
  const float* A = xp + (size_t)b * 262144;   // [c][p]
  const float* B = xq + (size_t)b * 262144;   // [c][q]
  float* C = ws + AFF_OFF + (size_t)b * 1048576;
  int tx = t & 15, ty = t >> 4;
  int row = t >> 4, col = (t & 15) * 4;
  float* As0 = shbuf;            // [16][64]
  float* As1 = shbuf + 1024;
  float* Bs0 = shbuf + 2048;
  float* Bs1 = shbuf + 3072;
  const float* Ag = A + (size_t)row * 1024 + pi * 64 + col;
  const float* Bg = B + (size_t)row * 1024 + qi * 64 + col;
  float4 ra = *(const float4*)Ag;
  float4 rb = *(const float4*)Bg;
  *(float4*)&As0[row * 64 + col] = ra;
  *(float4*)&Bs0[row * 64 + col] = rb;
  __syncthreads();
  float acc[4][4] = {};
  float na[4] = {}, nb[4] = {};
  const float* Asc = As0; const float* Bsc = Bs0;
  float* Asn = As1; float* Bsn = Bs1;
  for (int k0 = 16; k0 <= 256; k0 += 16){
    if (k0 < 256){
      ra = *(const float4*)(Ag + (size_t)k0 * 1024);
      rb = *(const float4*)(Bg + (size_t)k0 * 1024);
    }
    #pragma unroll
    for (int kk = 0; kk < 16; ++kk){
      float4 av = *(const float4*)&Asc[kk * 64 + ty * 4];
      float4 bv = *(const float4*)&Bsc[kk * 64 + tx * 4];
      float a4[4] = {av.x, av.y, av.z, av.w};
      float b4[4] = {bv.x, bv.y, bv.z, bv.w};
      #pragma unroll
      for (int i = 0; i < 4; ++i){
        na[i] = fmaf(a4[i], a4[i], na[i]);
        nb[i] = fmaf(b4[i], b4[i], nb[i]);
        #pragma unroll
        for (int j = 0; j < 4; ++j)
          acc[i][j] = fmaf(a4[i], b4[j], acc[i][j]);
      }
    }
    if (k0 < 256){
      *(float4*)&Asn[row * 64 + col] = ra;
      *(float4*)&Bsn[row * 64 + col] = rb;
      __syncthreads();
      float* tmp;
      tmp = (float*)Asc; Asc = Asn; Asn = tmp;
      tmp = (float*)Bsc; Bsc = Bsn; Bsn = tmp;
    }
  }
  float iva[4], ivb[4];
  #pragma unroll
  for (int i = 0; i < 4; ++i){
    iva[i] = 1.0f / fmaxf(sqrtf(na[i]), 1e-12f);
    ivb[i] = 1.0f / fmaxf(sqrtf(nb[i]), 1e-12f);
  }
  #pragma unroll
  for (int i = 0; i < 4; ++i){
    float iva_i = iva[i];
    float4 v = make_float4(acc[i][0] * iva_i * ivb[0], acc[i][1] * iva_i * ivb[1],
                           acc[i][2] * iva_i * ivb[2], acc[i][3] * iva_i * ivb[3]);
    *(float4*)&C[(size_t)(pi * 64 + ty * 4 + i) * 1024 + qi * 64 + tx * 4] = v;
  }
}

// ============ K2: composed 5^4 conv; 16-wide lanes (80 FMA / 7 LDS per row) ============
// lane: t = wv(2) | grp(4) | hsel(1) | whalf(1); unit = (hl = wv*2+hsel, w0 = whalf*16)
// 16 grp-lanes split the 125 (dl,dd,dh) rows; reduce-scatter over grp bits (shfl 4/8/16/32).
__global__ __launch_bounds__(256, 3) void conv_k(float* __restrict__ ws){
  __shared__ __align__(16) float slots[5 * SLOT + 1750];   // 12550 f = 50.2 KB -> 3 blocks/CU

  int bid0 = blockIdx.x;
  int t = threadIdx.x;
  int bid, nsteps, dstart;
  if (bid0 < 256){                      // double block: units 2p, 2p+1 (shared b,l0,hq)
    int c = bid0 & 7, r = bid0 >> 3;
    int p = c * 64 + r;                 // pair id, XCD-chunked
    bid = 2 * p;
    nsteps = 16;
    dstart = ((bid >> 1) & 1) * 16;
  } else {                              // single block
    int s = bid0 - 256;
    int c = s & 7, q = s >> 3;
    int p = c * 64 + 32 + (q >> 1);
    bid = 2 * p + (q & 1);
    nsteps = 8;
    dstart = (bid & 3) * 8;
  }
  int hq = (bid >> 2) & 3, l0 = (bid >> 4) & 31, b = bid >> 9;
  int h0 = hq * 8;
  const float* affB = ws + AFF_OFF + (size_t)b * 1048576;
  float* xc = ws + XC_OFF + (size_t)b * 1048576;
  const float* K8G = ws + K8_OFF;
  const float* KCg = ws + KC_OFF;
  const float* bias = ws + BIAS_OFF;
  const float* zp = ws + ZP_OFF;

  int cl = (l0 == 0) ? 0 : (l0 == 31) ? 2 : 1;
  int chB = (hq == 0) ? 0 : (hq == 3) ? 2 : 1;    // boundary-row h class (1 if none)

  // A-phase lane constants
  int wv = t >> 6;
  int whalf = t & 1, hsel = (t >> 1) & 1, g = (t >> 2) & 15;
  int hl = wv * 2 + hsel;
  int hA = h0 + hl;
  int chA = (hA == 0) ? 0 : (hA == 31) ? 2 : 1;
  int w0c = whalf * 16;
  bool isBnd = (hq == 0 && hl == 0) || (hq == 3 && hl == 7);
  int bndoff4 = isBnd ? 500 : 0;
  int bndoff1 = isBnd ? 125 : 0;
  int wlocal = ((g & 1) << 3) | ((g & 2) << 1) | ((g & 4) >> 1) | ((g & 8) >> 3);
  int wA = w0c + wlocal;

  // boundary-column (corr) lane constants
  int outB = t >> 4, subB = t & 15;
  int hlB = outB >> 1, wx31 = outB & 1;
  int hB = h0 + hlB;
  int chB2 = (hB == 0) ? 0 : (hB == 31) ? 2 : 1;
  int cwB = wx31 ? 2 : 0;
  int colB = wx31 ? 33 : 2;                        // aff column w'=31 / w'=0 in 36-wide rows
  bool isBndB = (hq == 0 && hlB == 0) || (hq == 3 && hlB == 7);
  int kcBase = KC_LDS + (isBndB ? 250 : 0) + wx31 * 125;
  // base handoff: lane (in wave) holding interior value at (hB, w=0/31):
  //   w=0: grp=0,whalf=0 -> lane 2*hsel;  w=31: grp=15,whalf=1 -> lane 61+2*hsel
  int local = t & 63;
  int hs_ = (local >> 5) & 1;
  int wx_ = (local >> 4) & 1;
  int srcL = wx_ ? (61 + 2 * hs_) : (2 * hs_);

  // staging global offsets (9 rounds x 256 lanes = 2160 floats/plane)
  int o0, o1, o2, o3, o4, o5, o6, o7, o8;
#define PRE(r) { int flat = (r)*256 + t; \
    int wi = flat % 36; int rest = flat / 36; int hi = rest % 12; int dl2 = rest / 12; \
    int lp_ = l0 + dl2 - 2, hp_ = h0 + hi - 2, wp_ = wi - 2; \
    bool ok = ((unsigned)lp_ < 32u) && ((unsigned)hp_ < 32u) && ((unsigned)wp_ < 32u); \
    o##r = ok ? (lp_ * 32768 + hp_ * 32 + wp_) : -1; }
  PRE(0) PRE(1) PRE(2) PRE(3) PRE(4) PRE(5) PRE(6) PRE(7) PRE(8)
#undef PRE

#define STG(r, sp_) { const float* s_ = (pOK_ && o##r >= 0) ? (affB + o##r + dpo_) : zp; \
    GLL4(s_, sp_ + (r)*256 + t); }
#define STAGE(si_, dpv_) do { \
    int dp_ = (dpv_); bool pOK_ = ((unsigned)dp_ < 32u); int dpo_ = dp_ * 1024; \
    float* sp_ = slots + (si_) * SLOT; \
    STG(0, sp_) STG(1, sp_) STG(2, sp_) STG(3, sp_) \
    STG(4, sp_) STG(5, sp_) STG(6, sp_) STG(7, sp_) \
    if (t < 112) sp_[2048 + t] = (pOK_ && o8 >= 0) ? affB[o8 + dpo_] : 0.f; \
  } while (0)

  // kv tables (traversal order) + Kc tables; SEPARATE prefix-aligned loops
  // (global_load_lds writes firstlane-base + laneid*4 — active lanes MUST be a
  //  per-wave prefix with linear offsets; never branch mid-wave to a new base.)
#define LOADKV(cdv_) do { int cd_ = (cdv_); \
    int clsI_ = ((cl * 3 + cd_) * 3 + 1) * 3 + 1; \
    int clsB_ = ((cl * 3 + cd_) * 3 + chB) * 3 + 1; \
    for (int r_ = 0; r_ < 5; ++r_){ \
      int i_ = r_ * 256 + t; \
      if (i_ < 1250){ \
        int u_, j_, cls_; \
        if (i_ < 500){ u_ = i_ >> 2; j_ = i_ & 3; cls_ = clsI_; } \
        else if (i_ < 1000){ u_ = (i_ - 500) >> 2; j_ = i_ & 3; cls_ = clsB_; } \
        else if (i_ < 1125){ u_ = i_ - 1000; j_ = 4; cls_ = clsI_; } \
        else { u_ = i_ - 1125; j_ = 4; cls_ = clsB_; } \
        int dl_, dd_, dh_; \
        if (u_ < 25){ dd_ = 0; dl_ = u_ / 5; dh_ = u_ - dl_ * 5; } \
        else { int g_ = u_ - 25; dd_ = 1 + g_ / 25; int r2_ = g_ - (dd_ - 1) * 25; \
               dl_ = r2_ / 5; dh_ = r2_ - dl_ * 5; } \
        int m_ = dl_ * 25 + dd_ * 5 + dh_; \
        GLL4(K8G + (size_t)cls_ * 1000 + m_ * 8 + j_, slots + KVQ_OFF + i_); \
      } \
    } \
    for (int r_ = 0; r_ < 2; ++r_){ \
      int i2_ = r_ * 256 + t; \
      if (i2_ < 500){ \
        int bnd_ = (i2_ >= 250) ? 1 : 0; \
        int u2_ = i2_ - bnd_ * 250; \
        int chS_ = bnd_ ? chB : 1; \
        GLL4(KCg + (size_t)(cl * 3 + cd_) * 750 + chS_ * 250 + u2_, \
             slots + KC_LDS + i2_); \
      } \
    } \
  } while (0)

#define MROW { \
    const float* rp = slots + addr; \
    float4 q0 = *(const float4*)rp; \
    float4 q1 = *(const float4*)(rp + 4); \
    float4 q2 = *(const float4*)(rp + 8); \
    float4 q3 = *(const float4*)(rp + 12); \
    float4 q4v = *(const float4*)(rp + 16); \
    float4 kqv = *(const float4*)(slots + kvqA); \
    float k4v = slots[kv4A]; \
    fma80(q0, q1, q2, q3, q4v, kqv, k4v, acc); }

  int cdCur = (dstart == 0) ? 0 : 1;
  LOADKV(cdCur);
  STAGE((dstart + 8)  % 5, dstart - 2);
  STAGE((dstart + 9)  % 5, dstart - 1);
  STAGE((dstart + 10) % 5, dstart);
  STAGE((dstart + 11) % 5, dstart + 1);
  STAGE((dstart + 12) % 5, dstart + 2);
  asm volatile("s_waitcnt vmcnt(0)" ::: "memory");
  __syncthreads();

  for (int s8 = 0; s8 < nsteps; ++s8){
    int d = dstart + s8;
    int cd = (d == 0) ? 0 : (d == 31) ? 2 : 1;
    if (cd != cdCur){                               // block-uniform, rare
      cdCur = cd;
      LOADKV(cd);
      asm volatile("s_waitcnt vmcnt(0)" ::: "memory");
      __syncthreads();
    }
    int scomp = (d + 3) % 5;                        // slot of plane d-2 (dd=0)

    float acc[16] = {0.f, 0.f, 0.f, 0.f, 0.f, 0.f, 0.f, 0.f,
                     0.f, 0.f, 0.f, 0.f, 0.f, 0.f, 0.f, 0.f};
    float corr = 0.f;

    // ---- phase 1: rows u=g, u=g+16 (all dd=0 reads done here) + corr rd=0 taps ----
    {
      int dlp = (g * 205) >> 10;
      int dhp = g - dlp * 5;
      int sip = scomp;
      int addr = sip * SLOT + (dlp * 12 + hl + dhp) * 36 + w0c;
      int kvqA = KVQ_OFF + bndoff4 + g * 4;
      int kv4A = KVQ_OFF + 1000 + bndoff1 + g;
      MROW
      addr += 1332; dhp += 1; dlp += 3; kvqA += 64; kv4A += 16;
      if (dhp >= 5){ dhp -= 5; dlp += 1; addr += 252; }
      if (dlp >= 5){ dlp -= 5; sip += 1; if (sip >= 5){ sip -= 5; addr -= 5 * SLOT; } }
      MROW
      int u = subB;
      #pragma unroll
      for (int k = 0; k < 2; ++k){
        if (u < 25){
          int rl = (u * 205) >> 10, rh = u - rl * 5;
          float kcv = slots[kcBase + u];
          float av = slots[scomp * SLOT + (rl * 12 + hlB + rh) * 36 + colB];
          corr = fmaf(kcv, av, corr);
        }
        u += 16;
      }
    }
    __syncthreads();                     // all reads of slot scomp done
    if (s8 < nsteps - 1) STAGE(scomp, d + 3);   // async: plane d+3 into slot scomp

    // ---- phase 2: rows u = g+32 .. 124 step 16 + corr rd>=1 taps ----
    {
      int u = g + 32;                    // dd == 1 for all lanes at start
      int rem = u - 25;
      int dlp = (rem * 205) >> 10;
      int dhp = rem - dlp * 5;
      int sip = scomp + 1; if (sip >= 5) sip -= 5;
      int addr = sip * SLOT + (dlp * 12 + hl + dhp) * 36 + w0c;
      int kvqA = KVQ_OFF + bndoff4 + u * 4;
      int kv4A = KVQ_OFF + 1000 + bndoff1 + u;
      for (; u < 125; u += 16){
        MROW
        addr += 1332; dhp += 1; dlp += 3; kvqA += 64; kv4A += 16;
        if (dhp >= 5){ dhp -= 5; dlp += 1; addr += 252; }
        if (dlp >= 5){ dlp -= 5; sip += 1; if (sip >= 5){ sip -= 5; addr -= 5 * SLOT; } }
      }
      int u2 = subB;
      #pragma unroll
      for (int k = 0; k < 7; ++k){
        if (u2 < 100){
          int rd = 1 + ((u2 * 41) >> 10);
          int rr = u2 - (rd - 1) * 25;
          int rl = (rr * 205) >> 10, rh = rr - rl * 5;
          int si2 = scomp + rd; if (si2 >= 5) si2 -= 5;
          float kcv = slots[kcBase + 25 + u2];
          float av = slots[si2 * SLOT + (rl * 12 + hlB + rh) * 36 + colB];
          corr = fmaf(kcv, av, corr);
        }
        u2 += 16;
      }
    }

    // ---- corr reduction (16 sub-lanes) ----
    corr += __shfl_xor(corr, 1);
    corr += __shfl_xor(corr, 2);
    corr += __shfl_xor(corr, 4);
    corr += __shfl_xor(corr, 8);

    // ---- A reduce-scatter butterfly over grp bits (15 shfl) ----
    float r;
    {
      bool c1 = (g & 1) != 0;
      float s8v[8], k8v[8];
      #pragma unroll
      for (int j = 0; j < 8; ++j){
        s8v[j] = c1 ? acc[j] : acc[j + 8];
        k8v[j] = c1 ? acc[j + 8] : acc[j];
      }
      #pragma unroll
      for (int j = 0; j < 8; ++j) k8v[j] += __shfl_xor(s8v[j], 4);
      bool c2 = (g & 2) != 0;
      float s4v[4], q4s[4];
      #pragma unroll
      for (int j = 0; j < 4; ++j){
        s4v[j] = c2 ? k8v[j] : k8v[j + 4];
        q4s[j] = c2 ? k8v[j + 4] : k8v[j];
      }
      #pragma unroll
      for (int j = 0; j < 4; ++j) q4s[j] += __shfl_xor(s4v[j], 8);
      bool c3 = (g & 4) != 0;
      float s2v[2], k2v[2];
      #pragma unroll
      for (int j = 0; j < 2; ++j){
        s2v[j] = c3 ? q4s[j] : q4s[j + 2];
        k2v[j] = c3 ? q4s[j + 2] : q4s[j];
      }
      #pragma unroll
      for (int j = 0; j < 2; ++j) k2v[j] += __shfl_xor(s2v[j], 16);
      bool c4 = (g & 8) != 0;
      float s1v = c4 ? k2v[0] : k2v[1];
      float k1v = c4 ? k2v[1] : k2v[0];
      r = k1v + __shfl_xor(s1v, 32);
    }

    // ---- base handoff: boundary-column groups pull interior value via shfl ----
    float baseR = __shfl(r, srcL);

    // ---- stores ----
    if (wA != 0 && wA != 31){
      float bvA = bias[l0 * 27 + cd * 9 + chA * 3 + 1];
      xc[(size_t)(l0 * 32 + d) * 1024 + hA * 32 + wA] = r + bvA;
    }
    if (subB == 0){
      float bvB = bias[l0 * 27 + cd * 9 + chB2 * 3 + cwB];
      xc[(size_t)(l0 * 32 + d) * 1024 + hB * 32 + (wx31 ? 31 : 0)] = baseR - corr + bvB;
    }

    asm volatile("s_waitcnt vmcnt(0)" ::: "memory");   // staged plane landed
    __syncthreads();
  }
#undef STG
#undef STAGE
#undef LOADKV
#undef MROW
}

// ============ K3: fused { valp top3 | valq stage1 } (no atomics) ============
__global__ __launch_bounds__(256) void top1_k(const float* __restrict__ ws, float* __restrict__ out){
  const float* xc = ws + XC_OFF;
  int bid = blockIdx.x;
  int t = threadIdx.x;

  if (bid < 512){
    // ---- valp: top3 over q per (b,p); wave per row ----
    int wid = bid * 4 + (t >> 6);
    int lane = t & 63;
    int b = wid >> 10, p = wid & 1023;
    const float4* row4 = (const float4*)(xc + (size_t)b * 1048576 + (size_t)p * 1024);
    float a0 = -3.4e38f, a1 = a0, a2 = a0;
    #pragma unroll
    for (int j = 0; j < 4; ++j){
      float4 v = row4[j * 64 + lane];
      ins3(a0, a1, a2, v.x); ins3(a0, a1, a2, v.y);
      ins3(a0, a1, a2, v.z); ins3(a0, a1, a2, v.w);
    }
    for (int off = 32; off; off >>= 1){
      float b0 = __shfl_xor(a0, off), b1 = __shfl_xor(a1, off), b2 = __shfl_xor(a2, off);
      ins3(a0, a1, a2, b0); ins3(a0, a1, a2, b1); ins3(a0, a1, a2, b2);
    }
    if (lane < 3){
      float v = (lane == 0) ? a0 : (lane == 1) ? a1 : a2;
      out[b * 3072 + lane * 1024 + p] = v;
    }
    return;
  }

  // ---- valq stage 1: partial top3 over 32 p's per (b,q) ----
  float* part = (float*)ws + PART_OFF;
  int b2 = bid - 512;                        // 256: b(2) x pc(32) x qq(4)
  int qq = b2 & 3, pc = (b2 >> 2) & 31, b = b2 >> 7;
  int q = qq * 256 + t;
  const float* base = xc + (size_t)b * 1048576 + q;
  float a0 = -3.4e38f, a1 = a0, a2 = a0;
  #pragma unroll 4
  for (int i = 0; i < 32; ++i) ins3(a0, a1, a2, base[(size_t)(pc * 32 + i) * 1024]);
  part[(size_t)((b * 32 + pc) * 3 + 0) * 1024 + q] = a0;
  part[(size_t)((b * 32 + pc) * 3 + 1) * 1024 + q] = a1;
  part[(size_t)((b * 32 + pc) * 3 + 2) * 1024 + q] = a2;
}

// ============ K4: valq stage 2 — 8 lanes per output, shfl-merged ============
__global__ __launch_bounds__(256) void top2_k(const float* __restrict__ ws, float* __restrict__ out){
  const float* part = ws + PART_OFF;
  int gid = blockIdx.x * 256 + threadIdx.x;   // 16384 = 2048 outputs x 8 lanes
  int sub = gid & 7;
  int oidx = gid >> 3;
  int b = oidx >> 10, q = oidx & 1023;
  float a0 = -3.4e38f, a1 = a0, a2 = a0;
  #pragma unroll
  for (int i = 0; i < 12; ++i){
    int c = sub + i * 8;
    ins3(a0, a1, a2, part[(size_t)(b * 96 + c) * 1024 + q]);
  }
  #pragma unroll
  for (int off = 1; off <= 4; off <<= 1){
    float b0 = __shfl_xor(a0, off), b1 = __shfl_xor(a1, off), b2 = __shfl_xor(a2, off);
    ins3(a0, a1, a2, b0); ins3(a0, a1, a2, b1); ins3(a0, a1, a2, b2);
  }
  if (sub == 0){
    out[6144 + b * 3072 + q] = a0;
    out[6144 + b * 3072 + 1024 + q] = a1;
    out[6144 + b * 3072 + 2048 + q] = a2;
  }
}

extern "C" void kernel_launch(void* const* d_in, const int* in_sizes, int n_in,
                              void* d_out, int out_size, void* d_ws, size_t ws_size,
                              hipStream_t stream){
  const float* xp = (const float*)d_in[0];
  const float* xq = (const float*)d_in[1];
  const float* W1 = (const float*)d_in[2];
  const float* B1 = (const float*)d_in[3];
  const float* W2 = (const float*)d_in[4];
  const float* B2 = (const float*)d_in[5];
  float* out = (float*)d_out;
  float* ws = (float*)d_ws;
  hipLaunchKernelGGL(ptab_k, dim3(26),  dim3(256), 0, stream, W1, W2, ws);
  hipLaunchKernelGGL(prep_k, dim3(863), dim3(256), 0, stream, xp, xq, W1, B1, W2, B2, ws);
  hipLaunchKernelGGL(conv_k, dim3(768), dim3(256), 0, stream, ws);
  hipLaunchKernelGGL(top1_k, dim3(768), dim3(256), 0, stream, ws, out);
  hipLaunchKernelGGL(top2_k, dim3(64),  dim3(256), 0, stream, ws, out);
}

// Round 18
// 139.879 us; speedup vs baseline: 1.6743x; 1.4245x over previous
//
#include <hip/hip_runtime.h>

// ---------------- workspace layout (float offsets) ----------------
#define AFF_OFF   0u         // [2][1024 p][1024 q]
#define XC_OFF    2097152u   // [2][1024 p][1024 q]
#define K8_OFF    4194304u   // Ktab8 [81 cls][125 item][8] (pad cols 5..7 = 0)
#define BIAS_OFF  4275328u   // [32 l][3 cd][3 ch][3 cw]
#define PART_OFF  4276224u   // topq partials [2][32][3][1024]
#define ZP_OFF    4476928u   // zero page (1024 floats)
#define KC_OFF    4477952u   // w-boundary correction kernels [9 cls2][3 ch][2 ws][125]
#define PTAB_OFF  4484704u   // P = W2^T W1, [81 q2][81 q1]
// total 4491265 floats ~ 17.97 MB

#define SLOT 2160            // ring-slot stride (floats); 5 slots; slot(P) = (P+10)%5
#define KVQ_OFF 10800        // kv tables in LDS: [int f4 500][bnd f4 500][int t4 125][bnd t4 125]
#define KC_LDS  12050        // Kc tables in LDS: [bnd(2)][ws(2)][125] = 500

static __device__ __forceinline__ int imax(int a, int b){ return a > b ? a : b; }
static __device__ __forceinline__ int imin(int a, int b){ return a < b ? a : b; }

static __device__ __forceinline__ void ins3(float& a0, float& a1, float& a2, float v){
  if (v > a0){ a2 = a1; a1 = a0; a0 = v; }
  else if (v > a1){ a2 = a1; a1 = v; }
  else if (v > a2){ a2 = v; }
}

// 5-tap x 16-output row conv: window f[20] from 5 float4s, taps kq+k4
static __device__ __forceinline__ void fma80(const float4 a, const float4 b, const float4 c,
                                             const float4 d, const float4 e,
                                             const float4 kq, const float k4, float* acc){
  float f[20] = {a.x, a.y, a.z, a.w, b.x, b.y, b.z, b.w, c.x, c.y, c.z, c.w,
                 d.x, d.y, d.z, d.w, e.x, e.y, e.z, e.w};
  float kv5[5] = {kq.x, kq.y, kq.z, kq.w, k4};
  #pragma unroll
  for (int dw = 0; dw < 5; ++dw)
    #pragma unroll
    for (int j = 0; j < 16; ++j)
      acc[j] = fmaf(kv5[dw], f[j + dw], acc[j]);
}

#define GLL4(gsrc, ldst) __builtin_amdgcn_global_load_lds( \
    (const __attribute__((address_space(1))) void*)(gsrc), \
    (__attribute__((address_space(3))) void*)(ldst), 4, 0, 0)

// ============ K0: P = W2^T W1 (81x81) ============
__global__ __launch_bounds__(256) void ptab_k(const float* __restrict__ W1,
                                              const float* __restrict__ W2,
                                              float* __restrict__ ws){
  int tid = blockIdx.x * 256 + threadIdx.x;
  if (tid < 6561){
    int q2 = tid / 81, q1 = tid - (tid / 81) * 81;
    float s = 0.f;
    #pragma unroll
    for (int co = 0; co < 16; ++co)
      s = fmaf(W2[co * 81 + q2], W1[co * 81 + q1], s);
    ws[PTAB_OFF + tid] = s;
  }
}

// ============ K1: fused { gemm(+norms) | tab (P-based) | bias block } ============
__global__ __launch_bounds__(256) void prep_k(const float* __restrict__ xp,
                                              const float* __restrict__ xq,
                                              const float* __restrict__ W1,
                                              const float* __restrict__ B1,
                                              const float* __restrict__ W2,
                                              const float* __restrict__ B2,
                                              float* __restrict__ ws){
  __shared__ __align__(16) float shbuf[7860];
  int bid0 = blockIdx.x;
  int t = threadIdx.x;

  if (bid0 == 863){
    // ---------------- bias block (cooperative, factorized) ----------------
    float* sW2b = shbuf;            // 1296
    float* sB1  = shbuf + 1296;     // 48
    float* sB2  = shbuf + 1344;     // 3
    float* b1e  = shbuf + 1348;     // [32 y][16 co]
    float* T    = shbuf + 1860;     // [3 i][27 cls][16 co]
    for (int i = t; i < 1296; i += 256) sW2b[i] = W2[i];
    if (t < 48) sB1[t] = B1[t];
    if (t < 3)  sB2[t] = B2[t];
    __syncthreads();
    for (int e = t; e < 512; e += 256){
      int y = e >> 4, co = e & 15;
      float s = 0.f;
      #pragma unroll
      for (int i2 = 0; i2 < 3; ++i2){
        int y2 = y + i2 - 1;
        if (y2 >= 0 && y2 < 32) s += sB1[i2 * 16 + co];
      }
      b1e[e] = s;
    }
    for (int e = t; e < 1296; e += 256){
      int co = e & 15;
      int ic = e >> 4;
      int i = ic / 27, cls = ic - i * 27;
      int cd = cls / 9, ch = (cls / 3) % 3, cw = cls % 3;
      int jlo = (cd == 0) ? 1 : 0, jhi = (cd == 2) ? 1 : 2;
      int klo = (ch == 0) ? 1 : 0, khi = (ch == 2) ? 1 : 2;
      int mlo = (cw == 0) ? 1 : 0, mhi = (cw == 2) ? 1 : 2;
      float s = 0.f;
      for (int j = jlo; j <= jhi; ++j)
        for (int k = klo; k <= khi; ++k)
          for (int m = mlo; m <= mhi; ++m)
            s += sW2b[co * 81 + ((i * 3 + j) * 3 + k) * 3 + m];
      T[e] = s;
    }
    __syncthreads();
    for (int e = t; e < 864; e += 256){
      int l = e / 27, cls = e - l * 27;
      float v = 0.f;
      #pragma unroll
      for (int i = 0; i < 3; ++i){
        int y = l + i - 1;
        if (y >= 0 && y < 32){
          v += sB2[i];
          const float* bp = b1e + y * 16;
          const float* Tp = T + (i * 27 + cls) * 16;
          #pragma unroll
          for (int co = 0; co < 16; ++co) v = fmaf(bp[co], Tp[co], v);
        }
      }
      ws[BIAS_OFF + e] = v;
    }
    return;
  }

  if (bid0 >= 512){
    // ---------------- tab part (351 blocks), P staged in LDS ----------------
    float* P = shbuf;
    for (int i = t; i < 6561; i += 256) P[i] = ws[PTAB_OFF + i];
    __syncthreads();
    int tid = (bid0 - 512) * 256 + t;
    if (tid < 50625){
      int c = tid / 625, r = tid % 625;
      int cw = c % 3, ch = (c / 3) % 3, cd = (c / 9) % 3, cl = c / 27;
      int rw = r % 5, rh = (r / 5) % 5, rd = (r / 25) % 5, rl = r / 125;
      int al0 = imax(0, rl - 2), al1 = imin(2, rl);
      if (cl == 0) al0 = imax(al0, 1);
      if (cl == 2) al1 = imin(al1, 1);
      int ad0 = imax(0, rd - 2), ad1 = imin(2, rd);
      if (cd == 0) ad0 = imax(ad0, 1);
      if (cd == 2) ad1 = imin(ad1, 1);
      int ah0 = imax(0, rh - 2), ah1 = imin(2, rh);
      if (ch == 0) ah0 = imax(ah0, 1);
      if (ch == 2) ah1 = imin(ah1, 1);
      int aw0 = imax(0, rw - 2), aw1 = imin(2, rw);
      if (cw == 0) aw0 = imax(aw0, 1);
      if (cw == 2) aw1 = imin(aw1, 1);
      float s = 0.f;
      for (int a = al0; a <= al1; ++a)
        for (int bq = ad0; bq <= ad1; ++bq)
          for (int cq = ah0; cq <= ah1; ++cq)
            for (int dq = aw0; dq <= aw1; ++dq){
              int q2 = ((a * 3 + bq) * 3 + cq) * 3 + dq;
              int q1 = (((rl - a) * 3 + (rd - bq)) * 3 + (rh - cq)) * 3 + (rw - dq);
              s += P[q2 * 81 + q1];
            }
      int item = (r * 205) >> 10;           // r/5
      int j = r - item * 5;
      ws[K8_OFF + (size_t)c * 1000 + item * 8 + j] = s;
    } else if (tid < 51489){
      // bias moved to dedicated block 863
    } else if (tid < 52513){
      ws[ZP_OFF + (tid - 51489)] = 0.f;                 // zero page
    } else if (tid < 82888){
      int u = tid - 52513;                              // pad cols 5..7 of Ktab8
      int c = u / 375, r2 = u % 375;
      int item = r2 / 3, j = 5 + r2 % 3;
      ws[K8_OFF + (size_t)c * 1000 + item * 8 + j] = 0.f;
    } else if (tid < 89638){
      // ---- Kc correction tables: [cls2 9][ch 3][ws 2][125 traversal] ----
      int u = tid - 82888;
      int cls2 = u / 750, rest = u % 750;
      int ch = rest / 250, r2 = rest % 250;
      int wsd = r2 / 125, ut = r2 % 125;
      int rd, rl, rh;
      if (ut < 25){ rd = 0; rl = ut / 5; rh = ut % 5; }
      else { int g = ut - 25; rd = 1 + g / 25; int rr = g % 25; rl = rr / 5; rh = rr % 5; }
      int cl = cls2 / 3, cd = cls2 % 3;
      int al0 = imax(0, rl - 2), al1 = imin(2, rl);
      if (cl == 0) al0 = imax(al0, 1);
      if (cl == 2) al1 = imin(al1, 1);
      int ad0 = imax(0, rd - 2), ad1 = imin(2, rd);
      if (cd == 0) ad0 = imax(ad0, 1);
      if (cd == 2) ad1 = imin(ad1, 1);
      int ah0 = imax(0, rh - 2), ah1 = imin(2, rh);
      if (ch == 0) ah0 = imax(ah0, 1);
      if (ch == 2) ah1 = imin(ah1, 1);
      int dq = wsd ? 2 : 0;           // excluded conv2 w-tap
      int q1w = wsd ? 0 : 2;          // surviving W1 w-tap (zero-pad kills others)
      float s = 0.f;
      for (int a = al0; a <= al1; ++a)
        for (int bq = ad0; bq <= ad1; ++bq)
          for (int cq = ah0; cq <= ah1; ++cq){
            int q2 = ((a * 3 + bq) * 3 + cq) * 3 + dq;
            int q1 = (((rl - a) * 3 + (rd - bq)) * 3 + (rh - cq)) * 3 + q1w;
            s += P[q2 * 81 + q1];
          }
      ws[KC_OFF + u] = s;
    }
    return;
  }

  // ---------------- gemm part (512 blocks), norms fused ----------------
  int bid = (bid0 & 7) * 64 + (bid0 >> 3);    // XCD swizzle (512 % 8 == 0)
  int qi = bid & 15, pi = (bid >> 4) & 15, b = bid >> 8;
  const float* A = xp + (size_t)b * 262144;   // [c][p]
  const float* B = xq + (size_t)b * 262144;   // [c][q]
  float* C = ws + AFF_OFF + (size_t)b * 1048576;
  int tx = t & 15, ty = t >> 4;
  int row = t >> 4, col = (t & 15) * 4;
  float* As0 = shbuf;            // [16][64]
  float* As1 = shbuf + 1024;
  float* Bs0 = shbuf + 2048;
  float* Bs1 = shbuf + 3072;
  const float* Ag = A + (size_t)row * 1024 + pi * 64 + col;
  const float* Bg = B + (size_t)row * 1024 + qi * 64 + col;
  float4 ra = *(const float4*)Ag;
  float4 rb = *(const float4*)Bg;
  *(float4*)&As0[row * 64 + col] = ra;
  *(float4*)&Bs0[row * 64 + col] = rb;
  __syncthreads();
  float acc[4][4] = {};
  float na[4] = {}, nb[4] = {};
  const float* Asc = As0; const float* Bsc = Bs0;
  float* Asn = As1; float* Bsn = Bs1;
  for (int k0 = 16; k0 <= 256; k0 += 16){
    if (k0 < 256){
      ra = *(const float4*)(Ag + (size_t)k0 * 1024);
      rb = *(const float4*)(Bg + (size_t)k0 * 1024);
    }
    #pragma unroll
    for (int kk = 0; kk < 16; ++kk){
      float4 av = *(const float4*)&Asc[kk * 64 + ty * 4];
      float4 bv = *(const float4*)&Bsc[kk * 64 + tx * 4];
      float a4[4] = {av.x, av.y, av.z, av.w};
      float b4[4] = {bv.x, bv.y, bv.z, bv.w};
      #pragma unroll
      for (int i = 0; i < 4; ++i){
        na[i] = fmaf(a4[i], a4[i], na[i]);
        nb[i] = fmaf(b4[i], b4[i], nb[i]);
        #pragma unroll
        for (int j = 0; j < 4; ++j)
          acc[i][j] = fmaf(a4[i], b4[j], acc[i][j]);
      }
    }
    if (k0 < 256){
      *(float4*)&Asn[row * 64 + col] = ra;
      *(float4*)&Bsn[row * 64 + col] = rb;
      __syncthreads();
      float* tmp;
      tmp = (float*)Asc; Asc = Asn; Asn = tmp;
      tmp = (float*)Bsc; Bsc = Bsn; Bsn = tmp;
    }
  }
  float iva[4], ivb[4];
  #pragma unroll
  for (int i = 0; i < 4; ++i){
    iva[i] = 1.0f / fmaxf(sqrtf(na[i]), 1e-12f);
    ivb[i] = 1.0f / fmaxf(sqrtf(nb[i]), 1e-12f);
  }
  #pragma unroll
  for (int i = 0; i < 4; ++i){
    float iva_i = iva[i];
    float4 v = make_float4(acc[i][0] * iva_i * ivb[0], acc[i][1] * iva_i * ivb[1],
                           acc[i][2] * iva_i * ivb[2], acc[i][3] * iva_i * ivb[3]);
    *(float4*)&C[(size_t)(pi * 64 + ty * 4 + i) * 1024 + qi * 64 + tx * 4] = v;
  }
}

// ============ K2: composed 5^4 conv; 16-wide lanes (80 FMA / 7 LDS per row) ============
// lane: t = wv(2) | grp(4) | hsel(1) | whalf(1); unit = (hl = wv*2+hsel, w0 = whalf*16)
// 16 grp-lanes split the 125 (dl,dd,dh) rows; reduce-scatter over grp bits (shfl 4/8/16/32).
__global__ __launch_bounds__(256, 3) void conv_k(float* __restrict__ ws){
  __shared__ __align__(16) float slots[5 * SLOT + 1750];   // 12550 f = 50.2 KB -> 3 blocks/CU

  int bid0 = blockIdx.x;
  int t = threadIdx.x;
  int bid, nsteps, dstart;
  if (bid0 < 256){                      // double block: units 2p, 2p+1 (shared b,l0,hq)
    int c = bid0 & 7, r = bid0 >> 3;
    int p = c * 64 + r;                 // pair id, XCD-chunked
    bid = 2 * p;
    nsteps = 16;
    dstart = ((bid >> 1) & 1) * 16;
  } else {                              // single block
    int s = bid0 - 256;
    int c = s & 7, q = s >> 3;
    int p = c * 64 + 32 + (q >> 1);
    bid = 2 * p + (q & 1);
    nsteps = 8;
    dstart = (bid & 3) * 8;
  }
  int hq = (bid >> 2) & 3, l0 = (bid >> 4) & 31, b = bid >> 9;
  int h0 = hq * 8;
  const float* affB = ws + AFF_OFF + (size_t)b * 1048576;
  float* xc = ws + XC_OFF + (size_t)b * 1048576;
  const float* K8G = ws + K8_OFF;
  const float* KCg = ws + KC_OFF;
  const float* bias = ws + BIAS_OFF;
  const float* zp = ws + ZP_OFF;

  int cl = (l0 == 0) ? 0 : (l0 == 31) ? 2 : 1;
  int chB = (hq == 0) ? 0 : (hq == 3) ? 2 : 1;    // boundary-row h class (1 if none)

  // A-phase lane constants
  int wv = t >> 6;
  int whalf = t & 1, hsel = (t >> 1) & 1, g = (t >> 2) & 15;
  int hl = wv * 2 + hsel;
  int hA = h0 + hl;
  int chA = (hA == 0) ? 0 : (hA == 31) ? 2 : 1;
  int w0c = whalf * 16;
  bool isBnd = (hq == 0 && hl == 0) || (hq == 3 && hl == 7);
  int bndoff4 = isBnd ? 500 : 0;
  int bndoff1 = isBnd ? 125 : 0;
  int wlocal = ((g & 1) << 3) | ((g & 2) << 1) | ((g & 4) >> 1) | ((g & 8) >> 3);
  int wA = w0c + wlocal;

  // boundary-column (corr) lane constants
  int outB = t >> 4, subB = t & 15;
  int hlB = outB >> 1, wx31 = outB & 1;
  int hB = h0 + hlB;
  int chB2 = (hB == 0) ? 0 : (hB == 31) ? 2 : 1;
  int cwB = wx31 ? 2 : 0;
  int colB = wx31 ? 33 : 2;                        // aff column w'=31 / w'=0 in 36-wide rows
  bool isBndB = (hq == 0 && hlB == 0) || (hq == 3 && hlB == 7);
  int kcBase = KC_LDS + (isBndB ? 250 : 0) + wx31 * 125;
  // base handoff: lane (in wave) holding interior value at (hB, w=0/31):
  //   w=0: grp=0,whalf=0 -> lane 2*hsel;  w=31: grp=15,whalf=1 -> lane 61+2*hsel
  int local = t & 63;
  int hs_ = (local >> 5) & 1;
  int wx_ = (local >> 4) & 1;
  int srcL = wx_ ? (61 + 2 * hs_) : (2 * hs_);

  // staging global offsets (9 rounds x 256 lanes = 2160 floats/plane)
  int o0, o1, o2, o3, o4, o5, o6, o7, o8;
#define PRE(r) { int flat = (r)*256 + t; \
    int wi = flat % 36; int rest = flat / 36; int hi = rest % 12; int dl2 = rest / 12; \
    int lp_ = l0 + dl2 - 2, hp_ = h0 + hi - 2, wp_ = wi - 2; \
    bool ok = ((unsigned)lp_ < 32u) && ((unsigned)hp_ < 32u) && ((unsigned)wp_ < 32u); \
    o##r = ok ? (lp_ * 32768 + hp_ * 32 + wp_) : -1; }
  PRE(0) PRE(1) PRE(2) PRE(3) PRE(4) PRE(5) PRE(6) PRE(7) PRE(8)
#undef PRE

#define STG(r, sp_) { const float* s_ = (pOK_ && o##r >= 0) ? (affB + o##r + dpo_) : zp; \
    GLL4(s_, sp_ + (r)*256 + t); }
#define STAGE(si_, dpv_) do { \
    int dp_ = (dpv_); bool pOK_ = ((unsigned)dp_ < 32u); int dpo_ = dp_ * 1024; \
    float* sp_ = slots + (si_) * SLOT; \
    STG(0, sp_) STG(1, sp_) STG(2, sp_) STG(3, sp_) \
    STG(4, sp_) STG(5, sp_) STG(6, sp_) STG(7, sp_) \
    if (t < 112) sp_[2048 + t] = (pOK_ && o8 >= 0) ? affB[o8 + dpo_] : 0.f; \
  } while (0)

  // kv tables (traversal order) + Kc tables; SEPARATE prefix-aligned loops
  // (global_load_lds writes firstlane-base + laneid*4 — active lanes MUST be a
  //  per-wave prefix with linear offsets; never branch mid-wave to a new base.)
#define LOADKV(cdv_) do { int cd_ = (cdv_); \
    int clsI_ = ((cl * 3 + cd_) * 3 + 1) * 3 + 1; \
    int clsB_ = ((cl * 3 + cd_) * 3 + chB) * 3 + 1; \
    for (int r_ = 0; r_ < 5; ++r_){ \
      int i_ = r_ * 256 + t; \
      if (i_ < 1250){ \
        int u_, j_, cls_; \
        if (i_ < 500){ u_ = i_ >> 2; j_ = i_ & 3; cls_ = clsI_; } \
        else if (i_ < 1000){ u_ = (i_ - 500) >> 2; j_ = i_ & 3; cls_ = clsB_; } \
        else if (i_ < 1125){ u_ = i_ - 1000; j_ = 4; cls_ = clsI_; } \
        else { u_ = i_ - 1125; j_ = 4; cls_ = clsB_; } \
        int dl_, dd_, dh_; \
        if (u_ < 25){ dd_ = 0; dl_ = u_ / 5; dh_ = u_ - dl_ * 5; } \
        else { int g_ = u_ - 25; dd_ = 1 + g_ / 25; int r2_ = g_ - (dd_ - 1) * 25; \
               dl_ = r2_ / 5; dh_ = r2_ - dl_ * 5; } \
        int m_ = dl_ * 25 + dd_ * 5 + dh_; \
        GLL4(K8G + (size_t)cls_ * 1000 + m_ * 8 + j_, slots + KVQ_OFF + i_); \
      } \
    } \
    for (int r_ = 0; r_ < 2; ++r_){ \
      int i2_ = r_ * 256 + t; \
      if (i2_ < 500){ \
        int bnd_ = (i2_ >= 250) ? 1 : 0; \
        int u2_ = i2_ - bnd_ * 250; \
        int chS_ = bnd_ ? chB : 1; \
        GLL4(KCg + (size_t)(cl * 3 + cd_) * 750 + chS_ * 250 + u2_, \
             slots + KC_LDS + i2_); \
      } \
    } \
  } while (0)

#define MROW { \
    const float* rp = slots + addr; \
    float4 q0 = *(const float4*)rp; \
    float4 q1 = *(const float4*)(rp + 4); \
    float4 q2 = *(const float4*)(rp + 8); \
    float4 q3 = *(const float4*)(rp + 12); \
    float4 q4v = *(const float4*)(rp + 16); \
    float4 kqv = *(const float4*)(slots + kvqA); \
    float k4v = slots[kv4A]; \
    fma80(q0, q1, q2, q3, q4v, kqv, k4v, acc); }

  int cdCur = (dstart == 0) ? 0 : 1;
  LOADKV(cdCur);
  STAGE((dstart + 8)  % 5, dstart - 2);
  STAGE((dstart + 9)  % 5, dstart - 1);
  STAGE((dstart + 10) % 5, dstart);
  STAGE((dstart + 11) % 5, dstart + 1);
  STAGE((dstart + 12) % 5, dstart + 2);
  asm volatile("s_waitcnt vmcnt(0)" ::: "memory");
  __syncthreads();

  for (int s8 = 0; s8 < nsteps; ++s8){
    int d = dstart + s8;
    int cd = (d == 0) ? 0 : (d == 31) ? 2 : 1;
    if (cd != cdCur){                               // block-uniform, rare
      cdCur = cd;
      LOADKV(cd);
      asm volatile("s_waitcnt vmcnt(0)" ::: "memory");
      __syncthreads();
    }
    int scomp = (d + 3) % 5;                        // slot of plane d-2 (dd=0)

    float acc[16] = {0.f, 0.f, 0.f, 0.f, 0.f, 0.f, 0.f, 0.f,
                     0.f, 0.f, 0.f, 0.f, 0.f, 0.f, 0.f, 0.f};
    float corr = 0.f;

    // ---- phase 1: rows u=g, u=g+16 (all dd=0 reads done here) + corr rd=0 taps ----
    {
      int dlp = (g * 205) >> 10;
      int dhp = g - dlp * 5;
      int sip = scomp;
      int addr = sip * SLOT + (dlp * 12 + hl + dhp) * 36 + w0c;
      int kvqA = KVQ_OFF + bndoff4 + g * 4;
      int kv4A = KVQ_OFF + 1000 + bndoff1 + g;
      MROW
      addr += 1332; dhp += 1; dlp += 3; kvqA += 64; kv4A += 16;
      if (dhp >= 5){ dhp -= 5; dlp += 1; addr += 252; }
      if (dlp >= 5){ dlp -= 5; sip += 1; if (sip >= 5){ sip -= 5; addr -= 5 * SLOT; } }
      MROW
      int u = subB;
      #pragma unroll
      for (int k = 0; k < 2; ++k){
        if (u < 25){
          int rl = (u * 205) >> 10, rh = u - rl * 5;
          float kcv = slots[kcBase + u];
          float av = slots[scomp * SLOT + (rl * 12 + hlB + rh) * 36 + colB];
          corr = fmaf(kcv, av, corr);
        }
        u += 16;
      }
    }
    __syncthreads();                     // all reads of slot scomp done
    if (s8 < nsteps - 1) STAGE(scomp, d + 3);   // async: plane d+3 into slot scomp

    // ---- phase 2: rows u = g+32 .. 124 step 16 + corr rd>=1 taps ----
    {
      int u = g + 32;                    // dd == 1 for all lanes at start
      int rem = u - 25;
      int dlp = (rem * 205) >> 10;
      int dhp = rem - dlp * 5;
      int sip = scomp + 1; if (sip >= 5) sip -= 5;
      int addr = sip * SLOT + (dlp * 12 + hl + dhp) * 36 + w0c;
      int kvqA = KVQ_OFF + bndoff4 + u * 4;
      int kv4A = KVQ_OFF + 1000 + bndoff1 + u;
      for (; u < 125; u += 16){
        MROW
        addr += 1332; dhp += 1; dlp += 3; kvqA += 64; kv4A += 16;
        if (dhp >= 5){ dhp -= 5; dlp += 1; addr += 252; }
        if (dlp >= 5){ dlp -= 5; sip += 1; if (sip >= 5){ sip -= 5; addr -= 5 * SLOT; } }
      }
      int u2 = subB;
      #pragma unroll
      for (int k = 0; k < 7; ++k){
        if (u2 < 100){
          int rd = 1 + ((u2 * 41) >> 10);
          int rr = u2 - (rd - 1) * 25;
          int rl = (rr * 205) >> 10, rh = rr - rl * 5;
          int si2 = scomp + rd; if (si2 >= 5) si2 -= 5;
          float kcv = slots[kcBase + 25 + u2];
          float av = slots[si2 * SLOT + (rl * 12 + hlB + rh) * 36 + colB];
          corr = fmaf(kcv, av, corr);
        }
        u2 += 16;
      }
    }

    // ---- corr reduction (16 sub-lanes) ----
    corr += __shfl_xor(corr, 1);
    corr += __shfl_xor(corr, 2);
    corr += __shfl_xor(corr, 4);
    corr += __shfl_xor(corr, 8);

    // ---- A reduce-scatter butterfly over grp bits (15 shfl) ----
    float r;
    {
      bool c1 = (g & 1) != 0;
      float s8v[8], k8v[8];
      #pragma unroll
      for (int j = 0; j < 8; ++j){
        s8v[j] = c1 ? acc[j] : acc[j + 8];
        k8v[j] = c1 ? acc[j + 8] : acc[j];
      }
      #pragma unroll
      for (int j = 0; j < 8; ++j) k8v[j] += __shfl_xor(s8v[j], 4);
      bool c2 = (g & 2) != 0;
      float s4v[4], q4s[4];
      #pragma unroll
      for (int j = 0; j < 4; ++j){
        s4v[j] = c2 ? k8v[j] : k8v[j + 4];
        q4s[j] = c2 ? k8v[j + 4] : k8v[j];
      }
      #pragma unroll
      for (int j = 0; j < 4; ++j) q4s[j] += __shfl_xor(s4v[j], 8);
      bool c3 = (g & 4) != 0;
      float s2v[2], k2v[2];
      #pragma unroll
      for (int j = 0; j < 2; ++j){
        s2v[j] = c3 ? q4s[j] : q4s[j + 2];
        k2v[j] = c3 ? q4s[j + 2] : q4s[j];
      }
      #pragma unroll
      for (int j = 0; j < 2; ++j) k2v[j] += __shfl_xor(s2v[j], 16);
      bool c4 = (g & 8) != 0;
      float s1v = c4 ? k2v[0] : k2v[1];
      float k1v = c4 ? k2v[1] : k2v[0];
      r = k1v + __shfl_xor(s1v, 32);
    }

    // ---- base handoff: boundary-column groups pull interior value via shfl ----
    float baseR = __shfl(r, srcL);

    // ---- stores ----
    if (wA != 0 && wA != 31){
      float bvA = bias[l0 * 27 + cd * 9 + chA * 3 + 1];
      xc[(size_t)(l0 * 32 + d) * 1024 + hA * 32 + wA] = r + bvA;
    }
    if (subB == 0){
      float bvB = bias[l0 * 27 + cd * 9 + chB2 * 3 + cwB];
      xc[(size_t)(l0 * 32 + d) * 1024 + hB * 32 + (wx31 ? 31 : 0)] = baseR - corr + bvB;
    }

    asm volatile("s_waitcnt vmcnt(0)" ::: "memory");   // staged plane landed
    __syncthreads();
  }
#undef STG
#undef STAGE
#undef LOADKV
#undef MROW
}

// ============ K3: fused { valp top3 | valq stage1 } (no atomics) ============
__global__ __launch_bounds__(256) void top1_k(const float* __restrict__ ws, float* __restrict__ out){
  const float* xc = ws + XC_OFF;
  int bid = blockIdx.x;
  int t = threadIdx.x;

  if (bid < 512){
    // ---- valp: top3 over q per (b,p); wave per row ----
    int wid = bid * 4 + (t >> 6);
    int lane = t & 63;
    int b = wid >> 10, p = wid & 1023;
    const float4* row4 = (const float4*)(xc + (size_t)b * 1048576 + (size_t)p * 1024);
    float a0 = -3.4e38f, a1 = a0, a2 = a0;
    #pragma unroll
    for (int j = 0; j < 4; ++j){
      float4 v = row4[j * 64 + lane];
      ins3(a0, a1, a2, v.x); ins3(a0, a1, a2, v.y);
      ins3(a0, a1, a2, v.z); ins3(a0, a1, a2, v.w);
    }
    for (int off = 32; off; off >>= 1){
      float b0 = __shfl_xor(a0, off), b1 = __shfl_xor(a1, off), b2 = __shfl_xor(a2, off);
      ins3(a0, a1, a2, b0); ins3(a0, a1, a2, b1); ins3(a0, a1, a2, b2);
    }
    if (lane < 3){
      float v = (lane == 0) ? a0 : (lane == 1) ? a1 : a2;
      out[b * 3072 + lane * 1024 + p] = v;
    }
    return;
  }

  // ---- valq stage 1: partial top3 over 32 p's per (b,q) ----
  float* part = (float*)ws + PART_OFF;
  int b2 = bid - 512;                        // 256: b(2) x pc(32) x qq(4)
  int qq = b2 & 3, pc = (b2 >> 2) & 31, b = b2 >> 7;
  int q = qq * 256 + t;
  const float* base = xc + (size_t)b * 1048576 + q;
  float a0 = -3.4e38f, a1 = a0, a2 = a0;
  #pragma unroll 4
  for (int i = 0; i < 32; ++i) ins3(a0, a1, a2, base[(size_t)(pc * 32 + i) * 1024]);
  part[(size_t)((b * 32 + pc) * 3 + 0) * 1024 + q] = a0;
  part[(size_t)((b * 32 + pc) * 3 + 1) * 1024 + q] = a1;
  part[(size_t)((b * 32 + pc) * 3 + 2) * 1024 + q] = a2;
}

// ============ K4: valq stage 2 — 8 lanes per output, shfl-merged ============
__global__ __launch_bounds__(256) void top2_k(const float* __restrict__ ws, float* __restrict__ out){
  const float* part = ws + PART_OFF;
  int gid = blockIdx.x * 256 + threadIdx.x;   // 16384 = 2048 outputs x 8 lanes
  int sub = gid & 7;
  int oidx = gid >> 3;
  int b = oidx >> 10, q = oidx & 1023;
  float a0 = -3.4e38f, a1 = a0, a2 = a0;
  #pragma unroll
  for (int i = 0; i < 12; ++i){
    int c = sub + i * 8;
    ins3(a0, a1, a2, part[(size_t)(b * 96 + c) * 1024 + q]);
  }
  #pragma unroll
  for (int off = 1; off <= 4; off <<= 1){
    float b0 = __shfl_xor(a0, off), b1 = __shfl_xor(a1, off), b2 = __shfl_xor(a2, off);
    ins3(a0, a1, a2, b0); ins3(a0, a1, a2, b1); ins3(a0, a1, a2, b2);
  }
  if (sub == 0){
    out[6144 + b * 3072 + q] = a0;
    out[6144 + b * 3072 + 1024 + q] = a1;
    out[6144 + b * 3072 + 2048 + q] = a2;
  }
}

extern "C" void kernel_launch(void* const* d_in, const int* in_sizes, int n_in,
                              void* d_out, int out_size, void* d_ws, size_t ws_size,
                              hipStream_t stream){
  const float* xp = (const float*)d_in[0];
  const float* xq = (const float*)d_in[1];
  const float* W1 = (const float*)d_in[2];
  const float* B1 = (const float*)d_in[3];
  const float* W2 = (const float*)d_in[4];
  const float* B2 = (const float*)d_in[5];
  float* out = (float*)d_out;
  float* ws = (float*)d_ws;
  hipLaunchKernelGGL(ptab_k, dim3(26),  dim3(256), 0, stream, W1, W2, ws);
  hipLaunchKernelGGL(prep_k, dim3(864), dim3(256), 0, stream, xp, xq, W1, B1, W2, B2, ws);
  hipLaunchKernelGGL(conv_k, dim3(768), dim3(256), 0, stream, ws);
  hipLaunchKernelGGL(top1_k, dim3(768), dim3(256), 0, stream, ws, out);
  hipLaunchKernelGGL(top2_k, dim3(64),  dim3(256), 0, stream, ws, out);
}